// Round 1
// baseline (236.906 us; speedup 1.0000x reference)
//
#include <hip/hip_runtime.h>

#define B_ 16
#define N_ 768
#define E_ 1024
#define H_ 16
#define D_ 64

typedef __bf16 bf16x8 __attribute__((ext_vector_type(8)));
typedef float f32x4 __attribute__((ext_vector_type(4)));
typedef unsigned short ushort8 __attribute__((ext_vector_type(8)));
typedef unsigned short ushort4v __attribute__((ext_vector_type(4)));
typedef unsigned short ushort2v __attribute__((ext_vector_type(2)));

__device__ __forceinline__ unsigned short f2bf(float x) {
  unsigned u = __builtin_bit_cast(unsigned, x);
  u += 0x7FFFu + ((u >> 16) & 1u);
  return (unsigned short)(u >> 16);
}

__device__ __forceinline__ f32x4 mfma16(ushort8 a, ushort8 b, f32x4 c) {
  return __builtin_amdgcn_mfma_f32_16x16x32_bf16(
      __builtin_bit_cast(bf16x8, a), __builtin_bit_cast(bf16x8, b), c, 0, 0, 0);
}

// ---------------- Wf -> bf16 ----------------
__global__ __launch_bounds__(256) void wf_kernel(const float* __restrict__ Wf,
                                                 unsigned short* __restrict__ Wfb) {
  size_t g = (size_t)blockIdx.x * 256 + threadIdx.x;  // 0..262143, 4 floats each
  float4 xv = *(const float4*)&Wf[g * 4];
  ushort4v s;
  s[0] = f2bf(xv.x); s[1] = f2bf(xv.y); s[2] = f2bf(xv.z); s[3] = f2bf(xv.w);
  *(ushort4v*)&Wfb[g * 4] = s;
}

// ---------------- per-head projections (MFMA) ----------------
// Outputs Qh,Kh,Vh in (B,H,N,D) bf16.
__global__ __launch_bounds__(256) void proj_kernel(
    const float* __restrict__ q, const float* __restrict__ k, const float* __restrict__ v,
    const float* __restrict__ Wq, const float* __restrict__ Wk, const float* __restrict__ Wv,
    unsigned short* __restrict__ Qh, unsigned short* __restrict__ Kh,
    unsigned short* __restrict__ Vh) {
  const int nt = blockIdx.x % 12;
  const int bh = blockIdx.x / 12;
  const int b = bh >> 4, h = bh & 15;
  const int tid = threadIdx.x;
  const int w = tid >> 6, l = tid & 63;
  const int l16 = l & 15, lg = l >> 4;

  __shared__ __align__(16) unsigned short Xs[3][64][72];
  __shared__ __align__(16) unsigned short Ws[3][64][72];

  const float* xin[3] = {q, k, v};
  const float* win[3] = {Wq, Wk, Wv};
  unsigned short* outp[3] = {Qh, Kh, Vh};

#pragma unroll
  for (int m = 0; m < 3; ++m) {
    const float* xp = xin[m];
#pragma unroll
    for (int i = 0; i < 4; ++i) {
      int flat = i * 256 + tid;       // 0..1023
      int row = flat >> 4;            // n-local 0..63
      int c4 = (flat & 15) * 4;       // d offset
      float4 xv = *(const float4*)&xp[((size_t)(b * N_ + nt * 64 + row)) * E_ + h * 64 + c4];
      ushort4v s;
      s[0] = f2bf(xv.x); s[1] = f2bf(xv.y); s[2] = f2bf(xv.z); s[3] = f2bf(xv.w);
      *(ushort4v*)&Xs[m][row][c4] = s;
    }
    const float* wp = win[m] + (size_t)h * 4096;  // W[h][e][d]
#pragma unroll
    for (int i = 0; i < 4; ++i) {
      int flat = i * 256 + tid;
      int row = flat >> 4;            // e 0..63
      int c4 = (flat & 15) * 4;       // d
      float4 wv = *(const float4*)&wp[row * 64 + c4];
      ushort4v s;
      s[0] = f2bf(wv.x); s[1] = f2bf(wv.y); s[2] = f2bf(wv.z); s[3] = f2bf(wv.w);
      *(ushort4v*)&Ws[m][row][c4] = s;
    }
  }
  __syncthreads();

#pragma unroll
  for (int m = 0; m < 3; ++m) {
    f32x4 acc[4] = {};
#pragma unroll
    for (int kc = 0; kc < 2; ++kc) {
      ushort8 a = *(const ushort8*)&Xs[m][w * 16 + l16][kc * 32 + lg * 8];
#pragma unroll
      for (int eg = 0; eg < 4; ++eg) {
        ushort8 bf = *(const ushort8*)&Ws[m][eg * 16 + l16][kc * 32 + lg * 8];
        acc[eg] = mfma16(a, bf, acc[eg]);
      }
    }
    unsigned short* op = outp[m];
#pragma unroll
    for (int eg = 0; eg < 4; ++eg)
#pragma unroll
      for (int r = 0; r < 4; ++r)
        op[((size_t)(b * H_ + h) * N_ + nt * 64 + w * 16 + lg * 4 + r) * 64 + eg * 16 + l16] =
            f2bf(acc[eg][r]);
  }
}

// ---------------- flash attention per (b,h,qtile) ----------------
__global__ __launch_bounds__(256) void attn_kernel(
    const unsigned short* __restrict__ Qh, const unsigned short* __restrict__ Kh,
    const unsigned short* __restrict__ Vh, const float* __restrict__ mask,
    unsigned short* __restrict__ attnO) {
  const int qt = blockIdx.x % 12;
  const int bh = blockIdx.x / 12;
  const int b = bh >> 4, h = bh & 15;
  const int tid = threadIdx.x;
  const int w = tid >> 6;
  const int l = tid & 63;
  const int l16 = l & 15, lg = l >> 4;

  __shared__ __align__(16) unsigned short Qs[64][72];
  __shared__ __align__(16) unsigned short Ks[64][72];
  __shared__ __align__(16) unsigned short Vs[64][72];  // transposed: Vs[d][k]
  __shared__ __align__(16) unsigned short Ps[4][16][72];
  __shared__ float badq[64];
  __shared__ float badk[64];

  const size_t baseQ = ((size_t)(b * H_ + h) * N_ + qt * 64) * 64;
  const size_t baseKV = (size_t)(b * H_ + h) * N_ * 64;

#pragma unroll
  for (int i = 0; i < 2; ++i) {
    int t = i * 256 + tid;
    int row = t >> 3, c8 = (t & 7) * 8;
    *(ushort8*)&Qs[row][c8] = *(const ushort8*)&Qh[baseQ + (size_t)row * 64 + c8];
  }
  if (tid < 64) badq[tid] = (mask[h * N_ + qt * 64 + tid] < -1e30f) ? 1.f : 0.f;
  __syncthreads();

  ushort8 aq[2];
  aq[0] = *(const ushort8*)&Qs[w * 16 + l16][lg * 8];
  aq[1] = *(const ushort8*)&Qs[w * 16 + l16][32 + lg * 8];

  f32x4 oacc[4] = {};
  float m_run[4], l_run[4];
#pragma unroll
  for (int r = 0; r < 4; ++r) { m_run[r] = -1e30f; l_run[r] = 0.f; }

  for (int kt = 0; kt < 12; ++kt) {
    __syncthreads();  // all waves done reading prev K/V tile
#pragma unroll
    for (int i = 0; i < 2; ++i) {
      int t = i * 256 + tid;
      int row = t >> 3, c8 = (t & 7) * 8;
      *(ushort8*)&Ks[row][c8] =
          *(const ushort8*)&Kh[baseKV + (size_t)(kt * 64 + row) * 64 + c8];
    }
    {  // V transposed staging: column-gather from global, contiguous LDS writes
      int d0 = (tid & 31) * 2;
      int k8 = tid >> 5;  // 0..7
      ushort8 va, vb;
#pragma unroll
      for (int j = 0; j < 8; ++j) {
        ushort2v p = *(const ushort2v*)&Vh[baseKV + (size_t)(kt * 64 + k8 * 8 + j) * 64 + d0];
        va[j] = p[0];
        vb[j] = p[1];
      }
      *(ushort8*)&Vs[d0][k8 * 8] = va;
      *(ushort8*)&Vs[d0 + 1][k8 * 8] = vb;
    }
    if (tid < 64) badk[tid] = (mask[h * N_ + kt * 64 + tid] < -1e30f) ? 1.f : 0.f;
    __syncthreads();

    // S = Q K^T  (16 q-rows per wave x 64 k-cols)
    f32x4 sacc[4] = {};
#pragma unroll
    for (int kc = 0; kc < 2; ++kc) {
#pragma unroll
      for (int cg = 0; cg < 4; ++cg) {
        ushort8 bk = *(const ushort8*)&Ks[cg * 16 + l16][kc * 32 + lg * 8];
        sacc[cg] = mfma16(aq[kc], bk, sacc[cg]);
      }
    }

    float bkf[4];
#pragma unroll
    for (int cg = 0; cg < 4; ++cg) bkf[cg] = badk[cg * 16 + l16];

#pragma unroll
    for (int r = 0; r < 4; ++r) {
      float bq = badq[w * 16 + lg * 4 + r];
      float s[4];
#pragma unroll
      for (int cg = 0; cg < 4; ++cg) {
        float sv = sacc[cg][r] * 0.03125f;  // 1/sqrt(E)=1/32
        s[cg] = (bq + bkf[cg] > 0.f) ? -1e16f : sv;  // OR semantics, exact f32 match
      }
      float mx = fmaxf(fmaxf(s[0], s[1]), fmaxf(s[2], s[3]));
#pragma unroll
      for (int off = 1; off < 16; off <<= 1) mx = fmaxf(mx, __shfl_xor(mx, off));
      float mnew = fmaxf(m_run[r], mx);
      float scl = __expf(m_run[r] - mnew);
      float rs = 0.f;
#pragma unroll
      for (int cg = 0; cg < 4; ++cg) {
        float p = __expf(s[cg] - mnew);
        rs += p;
        Ps[w][lg * 4 + r][cg * 16 + l16] = f2bf(p);
      }
#pragma unroll
      for (int off = 1; off < 16; off <<= 1) rs += __shfl_xor(rs, off);
      l_run[r] = l_run[r] * scl + rs;
      m_run[r] = mnew;
#pragma unroll
      for (int dg = 0; dg < 4; ++dg) oacc[dg][r] *= scl;
    }

    // O += P V   (P via per-wave LDS relayout C->A)
#pragma unroll
    for (int kc = 0; kc < 2; ++kc) {
      ushort8 ap = *(const ushort8*)&Ps[w][l16][kc * 32 + lg * 8];
#pragma unroll
      for (int dg = 0; dg < 4; ++dg) {
        ushort8 bv = *(const ushort8*)&Vs[dg * 16 + l16][kc * 32 + lg * 8];
        oacc[dg] = mfma16(ap, bv, oacc[dg]);
      }
    }
  }

  // epilogue: divide by softmax denom, write (B,N,E) bf16
#pragma unroll
  for (int r = 0; r < 4; ++r) {
    float inv = 1.f / l_run[r];
    int n = qt * 64 + w * 16 + lg * 4 + r;
    size_t orow = ((size_t)b * N_ + n) * E_ + h * 64;
#pragma unroll
    for (int dg = 0; dg < 4; ++dg)
      attnO[orow + dg * 16 + l16] = f2bf(oacc[dg][r] * inv);
  }
}

// ---------------- final GEMM: out = attn @ Wf^T ----------------
__global__ __launch_bounds__(256) void gemm_kernel(const unsigned short* __restrict__ A,
                                                   const unsigned short* __restrict__ Bm,
                                                   float* __restrict__ out) {
  const int be = blockIdx.x & 7;   // e tile 0..7
  const int bm = blockIdx.x >> 3;  // m tile 0..95
  const int tid = threadIdx.x;
  const int w = tid >> 6, l = tid & 63;
  const int l16 = l & 15, lg = l >> 4;
  const int wm = w >> 1, wn = w & 1;

  __shared__ __align__(16) unsigned short As[128][72];
  __shared__ __align__(16) unsigned short Bs[128][72];

  f32x4 acc[4][4] = {};
  const int m0 = bm * 128, e0 = be * 128;

  for (int kk = 0; kk < 16; ++kk) {
    __syncthreads();
#pragma unroll
    for (int i = 0; i < 4; ++i) {
      int flat = i * 256 + tid;  // 0..1023
      int row = flat >> 3;       // 0..127
      int c8 = (flat & 7) * 8;
      *(ushort8*)&As[row][c8] = *(const ushort8*)&A[(size_t)(m0 + row) * E_ + kk * 64 + c8];
      *(ushort8*)&Bs[row][c8] = *(const ushort8*)&Bm[(size_t)(e0 + row) * E_ + kk * 64 + c8];
    }
    __syncthreads();
#pragma unroll
    for (int kc = 0; kc < 2; ++kc) {
      ushort8 a[4], bf[4];
#pragma unroll
      for (int i = 0; i < 4; ++i)
        a[i] = *(const ushort8*)&As[wm * 64 + i * 16 + l16][kc * 32 + lg * 8];
#pragma unroll
      for (int j = 0; j < 4; ++j)
        bf[j] = *(const ushort8*)&Bs[wn * 64 + j * 16 + l16][kc * 32 + lg * 8];
#pragma unroll
      for (int i = 0; i < 4; ++i)
#pragma unroll
        for (int j = 0; j < 4; ++j) acc[i][j] = mfma16(a[i], bf[j], acc[i][j]);
    }
  }

#pragma unroll
  for (int i = 0; i < 4; ++i)
#pragma unroll
    for (int j = 0; j < 4; ++j)
#pragma unroll
      for (int r = 0; r < 4; ++r)
        out[(size_t)(m0 + wm * 64 + i * 16 + lg * 4 + r) * E_ + e0 + wn * 64 + j * 16 + l16] =
            acc[i][j][r];
}

extern "C" void kernel_launch(void* const* d_in, const int* in_sizes, int n_in,
                              void* d_out, int out_size, void* d_ws, size_t ws_size,
                              hipStream_t stream) {
  const float* q = (const float*)d_in[0];
  const float* k = (const float*)d_in[1];
  const float* v = (const float*)d_in[2];
  const float* mask = (const float*)d_in[3];
  const float* Wq = (const float*)d_in[4];
  const float* Wk = (const float*)d_in[5];
  const float* Wv = (const float*)d_in[6];
  const float* Wf = (const float*)d_in[7];
  float* out = (float*)d_out;

  const size_t PH = (size_t)B_ * H_ * N_ * D_;  // 12,582,912
  unsigned short* Qh = (unsigned short*)d_ws;
  unsigned short* Kh = Qh + PH;
  unsigned short* Vh = Kh + PH;
  unsigned short* attn = Vh + PH;
  unsigned short* Wfb = attn + PH;  // 1M elems; total ws use ~103 MB

  wf_kernel<<<(E_ * E_) / (256 * 4), 256, 0, stream>>>(Wf, Wfb);
  proj_kernel<<<B_ * H_ * (N_ / 64), 256, 0, stream>>>(q, k, v, Wq, Wk, Wv, Qh, Kh, Vh);
  attn_kernel<<<B_ * H_ * (N_ / 64), 256, 0, stream>>>(Qh, Kh, Vh, mask, attn);
  gemm_kernel<<<(B_ * N_ / 128) * (E_ / 128), 256, 0, stream>>>(attn, Wfb, out);
}

// Round 2
// 160.734 us; speedup vs baseline: 1.4739x; 1.4739x over previous
//
#include <hip/hip_runtime.h>

#define B_ 16
#define N_ 768
#define E_ 1024
#define H_ 16
#define D_ 64

typedef __bf16 bf16x8 __attribute__((ext_vector_type(8)));
typedef float f32x4 __attribute__((ext_vector_type(4)));
typedef unsigned short ushort8 __attribute__((ext_vector_type(8)));
typedef unsigned short ushort4v __attribute__((ext_vector_type(4)));
typedef unsigned int uint2v __attribute__((ext_vector_type(2)));
typedef unsigned int uint4v __attribute__((ext_vector_type(4)));

__device__ __forceinline__ unsigned short f2bf(float x) {
  unsigned u = __builtin_bit_cast(unsigned, x);
  u += 0x7FFFu + ((u >> 16) & 1u);
  return (unsigned short)(u >> 16);
}

__device__ __forceinline__ unsigned cvtpk(float lo, float hi) {
  unsigned r;
  asm("v_cvt_pk_bf16_f32 %0, %1, %2" : "=v"(r) : "v"(lo), "v"(hi));
  return r;
}

__device__ __forceinline__ f32x4 mfma16(ushort8 a, ushort8 b, f32x4 c) {
  return __builtin_amdgcn_mfma_f32_16x16x32_bf16(
      __builtin_bit_cast(bf16x8, a), __builtin_bit_cast(bf16x8, b), c, 0, 0, 0);
}

// ---------------- Wf -> bf16 ----------------
__global__ __launch_bounds__(256) void wf_kernel(const float* __restrict__ Wf,
                                                 unsigned short* __restrict__ Wfb) {
  size_t g = (size_t)blockIdx.x * 256 + threadIdx.x;
  float4 xv = *(const float4*)&Wf[g * 4];
  ushort4v s;
  s[0] = f2bf(xv.x); s[1] = f2bf(xv.y); s[2] = f2bf(xv.z); s[3] = f2bf(xv.w);
  *(ushort4v*)&Wfb[g * 4] = s;
}

// ---------------- per-head projections (MFMA) ----------------
// Qh,Kh in (B,H,N,D) bf16; V written TRANSPOSED as Vt (B,H,D,N) bf16.
__global__ __launch_bounds__(256) void proj_kernel(
    const float* __restrict__ q, const float* __restrict__ k, const float* __restrict__ v,
    const float* __restrict__ Wq, const float* __restrict__ Wk, const float* __restrict__ Wv,
    unsigned short* __restrict__ Qh, unsigned short* __restrict__ Kh,
    unsigned short* __restrict__ Vt) {
  const int nt = blockIdx.x % 12;
  const int bh = blockIdx.x / 12;
  const int b = bh >> 4, h = bh & 15;
  const int tid = threadIdx.x;
  const int w = tid >> 6, l = tid & 63;
  const int l16 = l & 15, lg = l >> 4;

  __shared__ __align__(16) unsigned short Xs[3][64][72];
  __shared__ __align__(16) unsigned short Ws[3][64][72];

  const float* xin[3] = {q, k, v};
  const float* win[3] = {Wq, Wk, Wv};

#pragma unroll
  for (int m = 0; m < 3; ++m) {
    const float* xp = xin[m];
#pragma unroll
    for (int i = 0; i < 4; ++i) {
      int flat = i * 256 + tid;
      int row = flat >> 4;
      int c4 = (flat & 15) * 4;
      float4 xv = *(const float4*)&xp[((size_t)(b * N_ + nt * 64 + row)) * E_ + h * 64 + c4];
      ushort4v s;
      s[0] = f2bf(xv.x); s[1] = f2bf(xv.y); s[2] = f2bf(xv.z); s[3] = f2bf(xv.w);
      *(ushort4v*)&Xs[m][row][c4] = s;
    }
    const float* wp = win[m] + (size_t)h * 4096;
#pragma unroll
    for (int i = 0; i < 4; ++i) {
      int flat = i * 256 + tid;
      int row = flat >> 4;
      int c4 = (flat & 15) * 4;
      float4 wv = *(const float4*)&wp[row * 64 + c4];
      ushort4v s;
      s[0] = f2bf(wv.x); s[1] = f2bf(wv.y); s[2] = f2bf(wv.z); s[3] = f2bf(wv.w);
      *(ushort4v*)&Ws[m][row][c4] = s;
    }
  }
  __syncthreads();

  f32x4 vacc[4];
#pragma unroll
  for (int m = 0; m < 3; ++m) {
    f32x4 acc[4] = {};
#pragma unroll
    for (int kc = 0; kc < 2; ++kc) {
      ushort8 a = *(const ushort8*)&Xs[m][w * 16 + l16][kc * 32 + lg * 8];
#pragma unroll
      for (int eg = 0; eg < 4; ++eg) {
        ushort8 bf = *(const ushort8*)&Ws[m][eg * 16 + l16][kc * 32 + lg * 8];
        acc[eg] = mfma16(a, bf, acc[eg]);
      }
    }
    if (m == 2) {
#pragma unroll
      for (int eg = 0; eg < 4; ++eg) vacc[eg] = acc[eg];
    } else {
      unsigned short* op = (m == 0) ? Qh : Kh;
#pragma unroll
      for (int eg = 0; eg < 4; ++eg)
#pragma unroll
        for (int r = 0; r < 4; ++r)
          op[((size_t)(b * H_ + h) * N_ + nt * 64 + w * 16 + lg * 4 + r) * 64 + eg * 16 + l16] =
              f2bf(acc[eg][r]);
    }
  }

  // transpose V tile through LDS (reuse Xs[0]): rows d, cols n-local
  __syncthreads();
#pragma unroll
  for (int eg = 0; eg < 4; ++eg) {
    uint2v pk;
    pk[0] = cvtpk(vacc[eg][0], vacc[eg][1]);
    pk[1] = cvtpk(vacc[eg][2], vacc[eg][3]);
    *(uint2v*)&Xs[0][eg * 16 + l16][w * 16 + lg * 4] = pk;
  }
  __syncthreads();
#pragma unroll
  for (int i = 0; i < 2; ++i) {
    int row = i * 32 + (tid >> 3), c8 = (tid & 7) * 8;
    *(ushort8*)&Vt[((size_t)bh * 64 + row) * N_ + nt * 64 + c8] =
        *(const ushort8*)&Xs[0][row][c8];
  }
}

// ---------------- flash attention per (b,h,qtile=128) ----------------
// Swapped QK^T (S^T via mfma(K,Q)); fixed-shift softmax (no online max);
// deferred denominator; P packed via cvt_pk -> b64 LDS writes.
__global__ __launch_bounds__(256, 4) void attn_kernel(
    const unsigned short* __restrict__ Qh, const unsigned short* __restrict__ Kh,
    const unsigned short* __restrict__ Vt, const float* __restrict__ mask,
    unsigned short* __restrict__ attnO) {
  const int bid = blockIdx.x;
  const int logical = (bid & 7) * 192 + (bid >> 3);  // XCD-chunked swizzle (1536%8==0)
  const int qt = logical % 6;
  const int bh = logical / 6;
  const int b = bh >> 4, h = bh & 15;
  const int tid = threadIdx.x;
  const int w = tid >> 6, l = tid & 63;
  const int l16 = l & 15, lg = l >> 4;

  __shared__ __align__(16) unsigned short Ks[64][72];
  __shared__ __align__(16) unsigned short Vs[64][72];
  __shared__ __align__(16) unsigned short Ps[4][32][72];
  __shared__ float badk[N_];

  const size_t baseK = (size_t)bh * N_ * 64;  // Kh (B,H,N,D)
  const size_t baseV = (size_t)bh * 64 * N_;  // Vt (B,H,D,N)
  const int qrow0 = qt * 128 + w * 32;

  for (int i = tid; i < N_; i += 256) badk[i] = (mask[h * N_ + i] < -1e30f) ? 1.f : 0.f;

  // Q fragments direct from global (read once)
  ushort8 bQ[2][2];
#pragma unroll
  for (int qs = 0; qs < 2; ++qs)
#pragma unroll
    for (int kc = 0; kc < 2; ++kc)
      bQ[qs][kc] = *(const ushort8*)&Qh[((size_t)bh * N_ + qrow0 + qs * 16 + l16) * 64 +
                                        kc * 32 + lg * 8];
  float bqf[2];
#pragma unroll
  for (int qs = 0; qs < 2; ++qs)
    bqf[qs] = (mask[h * N_ + qrow0 + qs * 16 + l16] < -1e30f) ? 1.f : 0.f;

  const int srow = tid >> 3;          // 0..31 (+32 for i=1)
  const int sc8 = (tid & 7) * 8;

  uint4v kreg[2], vreg[2];
#pragma unroll
  for (int i = 0; i < 2; ++i) {
    int row = i * 32 + srow;
    kreg[i] = *(const uint4v*)&Kh[baseK + (size_t)row * 64 + sc8];
    vreg[i] = *(const uint4v*)&Vt[baseV + (size_t)row * N_ + sc8];
  }
  __syncthreads();  // badk ready
#pragma unroll
  for (int i = 0; i < 2; ++i) {
    int row = i * 32 + srow;
    *(ushort8*)&Ks[row][sc8] = __builtin_bit_cast(ushort8, kreg[i]);
    *(ushort8*)&Vs[row][sc8] = __builtin_bit_cast(ushort8, vreg[i]);
  }
  __syncthreads();

  f32x4 oacc[2][4] = {};
  float l_part[2] = {0.f, 0.f};

  for (int kt = 0; kt < 12; ++kt) {
    if (kt < 11) {  // T14: issue next-tile loads early, write after barrier
#pragma unroll
      for (int i = 0; i < 2; ++i) {
        int row = i * 32 + srow;
        kreg[i] = *(const uint4v*)&Kh[baseK + (size_t)((kt + 1) * 64 + row) * 64 + sc8];
        vreg[i] = *(const uint4v*)&Vt[baseV + (size_t)row * N_ + (kt + 1) * 64 + sc8];
      }
    }

    // S^T tile-by-16 + softmax + pack (keeps register pressure low)
#pragma unroll
    for (int cg = 0; cg < 4; ++cg) {
      f32x4 st[2] = {};
#pragma unroll
      for (int kc = 0; kc < 2; ++kc) {
        ushort8 aK = *(const ushort8*)&Ks[cg * 16 + l16][kc * 32 + lg * 8];
#pragma unroll
        for (int qs = 0; qs < 2; ++qs) st[qs] = mfma16(aK, bQ[qs][kc], st[qs]);
      }
      f32x4 bk4 = *(const f32x4*)&badk[kt * 64 + cg * 16 + lg * 4];
#pragma unroll
      for (int qs = 0; qs < 2; ++qs) {
        float p[4];
#pragma unroll
        for (int r = 0; r < 4; ++r) {
          float t = st[qs][r] * 0.03125f;          // 1/sqrt(E)
          t = (bk4[r] > 0.f) ? -1e16f : t;         // masked k -> exp = 0
          t = (bqf[qs] > 0.f) ? 0.f : t;           // bad q row -> uniform
          p[r] = __expf(t);
          l_part[qs] += p[r];
        }
        uint2v pk;
        pk[0] = cvtpk(p[0], p[1]);
        pk[1] = cvtpk(p[2], p[3]);
        *(uint2v*)&Ps[w][qs * 16 + l16][cg * 16 + lg * 4] = pk;
      }
    }

    // O += P V
#pragma unroll
    for (int kc = 0; kc < 2; ++kc) {
      ushort8 ap[2];
#pragma unroll
      for (int qs = 0; qs < 2; ++qs)
        ap[qs] = *(const ushort8*)&Ps[w][qs * 16 + l16][kc * 32 + lg * 8];
#pragma unroll
      for (int dg = 0; dg < 4; ++dg) {
        ushort8 bv = *(const ushort8*)&Vs[dg * 16 + l16][kc * 32 + lg * 8];
#pragma unroll
        for (int qs = 0; qs < 2; ++qs) oacc[qs][dg] = mfma16(ap[qs], bv, oacc[qs][dg]);
      }
    }

    __syncthreads();
    if (kt < 11) {
#pragma unroll
      for (int i = 0; i < 2; ++i) {
        int row = i * 32 + srow;
        *(ushort8*)&Ks[row][sc8] = __builtin_bit_cast(ushort8, kreg[i]);
        *(ushort8*)&Vs[row][sc8] = __builtin_bit_cast(ushort8, vreg[i]);
      }
    }
    __syncthreads();
  }

  // epilogue: denominator reduce + write
#pragma unroll
  for (int qs = 0; qs < 2; ++qs) {
    float s = l_part[qs];
    s += __shfl_xor(s, 16);
    s += __shfl_xor(s, 32);  // all lanes: denom for q = qrow0 + qs*16 + l16
#pragma unroll
    for (int r = 0; r < 4; ++r) {
      float dnm = __shfl(s, lg * 4 + r);
      float inv = 1.f / dnm;
      int qg = qrow0 + qs * 16 + lg * 4 + r;
      size_t orow = ((size_t)b * N_ + qg) * E_ + h * 64;
#pragma unroll
      for (int dg = 0; dg < 4; ++dg)
        attnO[orow + dg * 16 + l16] = f2bf(oacc[qs][dg][r] * inv);
    }
  }
}

// ---------------- final GEMM: out = attn @ Wf^T ----------------
__global__ __launch_bounds__(256) void gemm_kernel(const unsigned short* __restrict__ A,
                                                   const unsigned short* __restrict__ Bm,
                                                   float* __restrict__ out) {
  const int be = blockIdx.x & 7;
  const int bm = blockIdx.x >> 3;
  const int tid = threadIdx.x;
  const int w = tid >> 6, l = tid & 63;
  const int l16 = l & 15, lg = l >> 4;
  const int wm = w >> 1, wn = w & 1;

  __shared__ __align__(16) unsigned short As[128][72];
  __shared__ __align__(16) unsigned short Bs[128][72];

  f32x4 acc[4][4] = {};
  const int m0 = bm * 128, e0 = be * 128;

  for (int kk = 0; kk < 16; ++kk) {
    __syncthreads();
#pragma unroll
    for (int i = 0; i < 4; ++i) {
      int flat = i * 256 + tid;
      int row = flat >> 3;
      int c8 = (flat & 7) * 8;
      *(ushort8*)&As[row][c8] = *(const ushort8*)&A[(size_t)(m0 + row) * E_ + kk * 64 + c8];
      *(ushort8*)&Bs[row][c8] = *(const ushort8*)&Bm[(size_t)(e0 + row) * E_ + kk * 64 + c8];
    }
    __syncthreads();
#pragma unroll
    for (int kc = 0; kc < 2; ++kc) {
      ushort8 a[4], bf[4];
#pragma unroll
      for (int i = 0; i < 4; ++i)
        a[i] = *(const ushort8*)&As[wm * 64 + i * 16 + l16][kc * 32 + lg * 8];
#pragma unroll
      for (int j = 0; j < 4; ++j)
        bf[j] = *(const ushort8*)&Bs[wn * 64 + j * 16 + l16][kc * 32 + lg * 8];
#pragma unroll
      for (int i = 0; i < 4; ++i)
#pragma unroll
        for (int j = 0; j < 4; ++j) acc[i][j] = mfma16(a[i], bf[j], acc[i][j]);
    }
  }

#pragma unroll
  for (int i = 0; i < 4; ++i)
#pragma unroll
    for (int j = 0; j < 4; ++j)
#pragma unroll
      for (int r = 0; r < 4; ++r)
        out[(size_t)(m0 + wm * 64 + i * 16 + lg * 4 + r) * E_ + e0 + wn * 64 + j * 16 + l16] =
            acc[i][j][r];
}

extern "C" void kernel_launch(void* const* d_in, const int* in_sizes, int n_in,
                              void* d_out, int out_size, void* d_ws, size_t ws_size,
                              hipStream_t stream) {
  const float* q = (const float*)d_in[0];
  const float* k = (const float*)d_in[1];
  const float* v = (const float*)d_in[2];
  const float* mask = (const float*)d_in[3];
  const float* Wq = (const float*)d_in[4];
  const float* Wk = (const float*)d_in[5];
  const float* Wv = (const float*)d_in[6];
  const float* Wf = (const float*)d_in[7];
  float* out = (float*)d_out;

  const size_t PH = (size_t)B_ * H_ * N_ * D_;
  unsigned short* Qh = (unsigned short*)d_ws;
  unsigned short* Kh = Qh + PH;
  unsigned short* Vt = Kh + PH;
  unsigned short* attn = Vt + PH;
  unsigned short* Wfb = attn + PH;

  wf_kernel<<<(E_ * E_) / (256 * 4), 256, 0, stream>>>(Wf, Wfb);
  proj_kernel<<<B_ * H_ * (N_ / 64), 256, 0, stream>>>(q, k, v, Wq, Wk, Wv, Qh, Kh, Vt);
  attn_kernel<<<B_ * H_ * (N_ / 128), 256, 0, stream>>>(Qh, Kh, Vt, mask, attn);
  gemm_kernel<<<(B_ * N_ / 128) * (E_ / 128), 256, 0, stream>>>(attn, Wfb, out);
}

// Round 3
// 158.245 us; speedup vs baseline: 1.4971x; 1.0157x over previous
//
#include <hip/hip_runtime.h>

#define B_ 16
#define N_ 768
#define E_ 1024
#define H_ 16
#define D_ 64

typedef __bf16 bf16x8 __attribute__((ext_vector_type(8)));
typedef float f32x4 __attribute__((ext_vector_type(4)));
typedef unsigned short ushort8 __attribute__((ext_vector_type(8)));
typedef unsigned short ushort4v __attribute__((ext_vector_type(4)));
typedef unsigned int uint2v __attribute__((ext_vector_type(2)));
typedef unsigned int uint4v __attribute__((ext_vector_type(4)));

__device__ __forceinline__ unsigned short f2bf(float x) {
  unsigned u = __builtin_bit_cast(unsigned, x);
  u += 0x7FFFu + ((u >> 16) & 1u);
  return (unsigned short)(u >> 16);
}

__device__ __forceinline__ unsigned cvtpk(float lo, float hi) {
  unsigned r;
  asm("v_cvt_pk_bf16_f32 %0, %1, %2" : "=v"(r) : "v"(lo), "v"(hi));
  return r;
}

__device__ __forceinline__ float fexp2(float x) {
  float r;
  asm("v_exp_f32 %0, %1" : "=v"(r) : "v"(x));
  return r;
}

__device__ __forceinline__ f32x4 mfma16(ushort8 a, ushort8 b, f32x4 c) {
  return __builtin_amdgcn_mfma_f32_16x16x32_bf16(
      __builtin_bit_cast(bf16x8, a), __builtin_bit_cast(bf16x8, b), c, 0, 0, 0);
}

// ---------------- Wf -> bf16 ----------------
__global__ __launch_bounds__(256) void wf_kernel(const float* __restrict__ Wf,
                                                 unsigned short* __restrict__ Wfb) {
  size_t g = (size_t)blockIdx.x * 256 + threadIdx.x;
  float4 xv = *(const float4*)&Wf[g * 4];
  ushort4v s;
  s[0] = f2bf(xv.x); s[1] = f2bf(xv.y); s[2] = f2bf(xv.z); s[3] = f2bf(xv.w);
  *(ushort4v*)&Wfb[g * 4] = s;
}

// ---------------- per-head projections (MFMA) ----------------
__global__ __launch_bounds__(256) void proj_kernel(
    const float* __restrict__ q, const float* __restrict__ k, const float* __restrict__ v,
    const float* __restrict__ Wq, const float* __restrict__ Wk, const float* __restrict__ Wv,
    unsigned short* __restrict__ Qh, unsigned short* __restrict__ Kh,
    unsigned short* __restrict__ Vt) {
  const int nt = blockIdx.x % 12;
  const int bh = blockIdx.x / 12;
  const int b = bh >> 4, h = bh & 15;
  const int tid = threadIdx.x;
  const int w = tid >> 6, l = tid & 63;
  const int l16 = l & 15, lg = l >> 4;

  __shared__ __align__(16) unsigned short Xs[3][64][72];
  __shared__ __align__(16) unsigned short Ws[3][64][72];

  const float* xin[3] = {q, k, v};
  const float* win[3] = {Wq, Wk, Wv};

#pragma unroll
  for (int m = 0; m < 3; ++m) {
    const float* xp = xin[m];
#pragma unroll
    for (int i = 0; i < 4; ++i) {
      int flat = i * 256 + tid;
      int row = flat >> 4;
      int c4 = (flat & 15) * 4;
      float4 xv = *(const float4*)&xp[((size_t)(b * N_ + nt * 64 + row)) * E_ + h * 64 + c4];
      ushort4v s;
      s[0] = f2bf(xv.x); s[1] = f2bf(xv.y); s[2] = f2bf(xv.z); s[3] = f2bf(xv.w);
      *(ushort4v*)&Xs[m][row][c4] = s;
    }
    const float* wp = win[m] + (size_t)h * 4096;
#pragma unroll
    for (int i = 0; i < 4; ++i) {
      int flat = i * 256 + tid;
      int row = flat >> 4;
      int c4 = (flat & 15) * 4;
      float4 wv = *(const float4*)&wp[row * 64 + c4];
      ushort4v s;
      s[0] = f2bf(wv.x); s[1] = f2bf(wv.y); s[2] = f2bf(wv.z); s[3] = f2bf(wv.w);
      *(ushort4v*)&Ws[m][row][c4] = s;
    }
  }
  __syncthreads();

  f32x4 vacc[4];
#pragma unroll
  for (int m = 0; m < 3; ++m) {
    f32x4 acc[4] = {};
#pragma unroll
    for (int kc = 0; kc < 2; ++kc) {
      ushort8 a = *(const ushort8*)&Xs[m][w * 16 + l16][kc * 32 + lg * 8];
#pragma unroll
      for (int eg = 0; eg < 4; ++eg) {
        ushort8 bf = *(const ushort8*)&Ws[m][eg * 16 + l16][kc * 32 + lg * 8];
        acc[eg] = mfma16(a, bf, acc[eg]);
      }
    }
    if (m == 2) {
#pragma unroll
      for (int eg = 0; eg < 4; ++eg) vacc[eg] = acc[eg];
    } else {
      unsigned short* op = (m == 0) ? Qh : Kh;
#pragma unroll
      for (int eg = 0; eg < 4; ++eg)
#pragma unroll
        for (int r = 0; r < 4; ++r)
          op[((size_t)(b * H_ + h) * N_ + nt * 64 + w * 16 + lg * 4 + r) * 64 + eg * 16 + l16] =
              f2bf(acc[eg][r]);
    }
  }

  __syncthreads();
#pragma unroll
  for (int eg = 0; eg < 4; ++eg) {
    uint2v pk;
    pk[0] = cvtpk(vacc[eg][0], vacc[eg][1]);
    pk[1] = cvtpk(vacc[eg][2], vacc[eg][3]);
    *(uint2v*)&Xs[0][eg * 16 + l16][w * 16 + lg * 4] = pk;
  }
  __syncthreads();
#pragma unroll
  for (int i = 0; i < 2; ++i) {
    int row = i * 32 + (tid >> 3), c8 = (tid & 7) * 8;
    *(ushort8*)&Vt[((size_t)bh * 64 + row) * N_ + nt * 64 + c8] =
        *(const ushort8*)&Xs[0][row][c8];
  }
}

// ---------------- flash attention per (b,h,qtile=128) ----------------
// In-register P via cvt_pk + permlane32/16 swaps; single barrier per kt
// (double-buffered K/V LDS); lean softmax: fma + v_exp + cndmask + add.
__global__ __launch_bounds__(256) void attn_kernel(
    const unsigned short* __restrict__ Qh, const unsigned short* __restrict__ Kh,
    const unsigned short* __restrict__ Vt, const float* __restrict__ mask,
    unsigned short* __restrict__ attnO) {
  const int bid = blockIdx.x;
  const int logical = (bid & 7) * 192 + (bid >> 3);  // XCD-chunked swizzle
  const int qt = logical % 6;
  const int bh = logical / 6;
  const int b = bh >> 4, h = bh & 15;
  const int tid = threadIdx.x;
  const int w = tid >> 6, l = tid & 63;
  const int l16 = l & 15, lg = l >> 4;

  __shared__ __align__(16) unsigned short Ks[2][64][72];
  __shared__ __align__(16) unsigned short Vs[2][64][72];
  __shared__ __align__(16) float addk[N_];

  const size_t baseK = (size_t)bh * N_ * 64;
  const size_t baseV = (size_t)bh * 64 * N_;
  const int qrow0 = qt * 128 + w * 32;
  const float C2 = 0.04508422f;  // log2(e)/32

  for (int i = tid; i < N_; i += 256)
    addk[i] = (mask[h * N_ + i] < -1e30f) ? -1000.0f : 0.0f;

  // Q fragments direct from global (read once, reused 12x)
  ushort8 bQ[2][2];
#pragma unroll
  for (int qs = 0; qs < 2; ++qs)
#pragma unroll
    for (int kc = 0; kc < 2; ++kc)
      bQ[qs][kc] = *(const ushort8*)&Qh[((size_t)bh * N_ + qrow0 + qs * 16 + l16) * 64 +
                                        kc * 32 + lg * 8];
  float bqf[2];
#pragma unroll
  for (int qs = 0; qs < 2; ++qs)
    bqf[qs] = (mask[h * N_ + qrow0 + qs * 16 + l16] < -1e30f) ? 1.f : 0.f;

  const int srow = tid >> 3;      // 0..31
  const int sc8 = (tid & 7) * 8;
  const unsigned short* kb = Kh + baseK + (size_t)srow * 64 + sc8;
  const unsigned short* vb = Vt + baseV + (size_t)srow * N_ + sc8;

  // prologue: stage tile 0 into buffer 0
  uint4v kreg[2], vreg[2];
#pragma unroll
  for (int i = 0; i < 2; ++i) {
    kreg[i] = *(const uint4v*)(kb + (size_t)i * 32 * 64);
    vreg[i] = *(const uint4v*)(vb + (size_t)i * 32 * N_);
  }
#pragma unroll
  for (int i = 0; i < 2; ++i) {
    *(ushort8*)&Ks[0][i * 32 + srow][sc8] = __builtin_bit_cast(ushort8, kreg[i]);
    *(ushort8*)&Vs[0][i * 32 + srow][sc8] = __builtin_bit_cast(ushort8, vreg[i]);
  }

  f32x4 oacc[2][4] = {};
  float l_part[2] = {0.f, 0.f};

  for (int kt = 0; kt < 12; ++kt) {
    __syncthreads();  // prev buffer reads done + current buffer writes visible
    const int cur = kt & 1;

    if (kt < 11) {  // issue next-tile loads; land during compute below
#pragma unroll
      for (int i = 0; i < 2; ++i) {
        kreg[i] = *(const uint4v*)(kb + (size_t)(kt + 1) * 4096 + (size_t)i * 2048);
        vreg[i] = *(const uint4v*)(vb + (size_t)(kt + 1) * 64 + (size_t)i * 32 * N_);
      }
    }

    // S^T = K Q^T  (64 k-rows x 32 q-cols per wave)
    f32x4 st[4][2] = {};
#pragma unroll
    for (int kc = 0; kc < 2; ++kc) {
#pragma unroll
      for (int cg = 0; cg < 4; ++cg) {
        ushort8 aK = *(const ushort8*)&Ks[cur][cg * 16 + l16][kc * 32 + lg * 8];
        st[cg][0] = mfma16(aK, bQ[0][kc], st[cg][0]);
        st[cg][1] = mfma16(aK, bQ[1][kc], st[cg][1]);
      }
    }

    // softmax: p = 2^(s*log2e/32 + addk) ; bad-q rows -> p = 1 (uniform)
#pragma unroll
    for (int cg = 0; cg < 4; ++cg) {
      f32x4 ak4 = *(const f32x4*)&addk[kt * 64 + cg * 16 + lg * 4];
#pragma unroll
      for (int qs = 0; qs < 2; ++qs) {
#pragma unroll
        for (int r = 0; r < 4; ++r) {
          float t = __builtin_fmaf(st[cg][qs][r], C2, ak4[r]);
          float e = fexp2(t);
          float p = (bqf[qs] > 0.f) ? 1.0f : e;
          l_part[qs] += p;
          st[cg][qs][r] = p;
        }
      }
    }

    // pack P into A-fragments in-register, then PV
#pragma unroll
    for (int kcP = 0; kcP < 2; ++kcP) {
      ushort8 pa[2];
#pragma unroll
      for (int qs = 0; qs < 2; ++qs) {
        unsigned a0 = cvtpk(st[2 * kcP][qs][0], st[2 * kcP][qs][1]);
        unsigned b0 = cvtpk(st[2 * kcP][qs][2], st[2 * kcP][qs][3]);
        unsigned a1 = cvtpk(st[2 * kcP + 1][qs][0], st[2 * kcP + 1][qs][1]);
        unsigned b1 = cvtpk(st[2 * kcP + 1][qs][2], st[2 * kcP + 1][qs][3]);
        asm("v_permlane32_swap_b32 %0, %1" : "+v"(a0), "+v"(a1));
        asm("v_permlane16_swap_b32 %0, %1" : "+v"(a0), "+v"(a1));
        asm("v_permlane32_swap_b32 %0, %1" : "+v"(b0), "+v"(b1));
        asm("v_permlane16_swap_b32 %0, %1" : "+v"(b0), "+v"(b1));
        uint4v pk;
        pk[0] = a0; pk[1] = b0; pk[2] = a1; pk[3] = b1;
        pa[qs] = __builtin_bit_cast(ushort8, pk);
      }
#pragma unroll
      for (int dg = 0; dg < 4; ++dg) {
        ushort8 bv = *(const ushort8*)&Vs[cur][dg * 16 + l16][kcP * 32 + lg * 8];
        oacc[0][dg] = mfma16(pa[0], bv, oacc[0][dg]);
        oacc[1][dg] = mfma16(pa[1], bv, oacc[1][dg]);
      }
    }

    if (kt < 11) {  // write next tile into the other buffer
#pragma unroll
      for (int i = 0; i < 2; ++i) {
        *(ushort8*)&Ks[cur ^ 1][i * 32 + srow][sc8] = __builtin_bit_cast(ushort8, kreg[i]);
        *(ushort8*)&Vs[cur ^ 1][i * 32 + srow][sc8] = __builtin_bit_cast(ushort8, vreg[i]);
      }
    }
  }

  // epilogue: denominator reduce + write
#pragma unroll
  for (int qs = 0; qs < 2; ++qs) {
    float s = l_part[qs];
    s += __shfl_xor(s, 16);
    s += __shfl_xor(s, 32);
#pragma unroll
    for (int r = 0; r < 4; ++r) {
      float dnm = __shfl(s, lg * 4 + r);
      float inv = 1.f / dnm;
      int qg = qrow0 + qs * 16 + lg * 4 + r;
      size_t orow = ((size_t)b * N_ + qg) * E_ + h * 64;
#pragma unroll
      for (int dg = 0; dg < 4; ++dg)
        attnO[orow + dg * 16 + l16] = f2bf(oacc[qs][dg][r] * inv);
    }
  }
}

// ---------------- final GEMM: out = attn @ Wf^T ----------------
// Reg-staged with T14 ordering: next-tile loads issue right after the
// compute barrier so HBM/L2 latency hides under the 32 MFMAs.
__global__ __launch_bounds__(256) void gemm_kernel(const unsigned short* __restrict__ A,
                                                   const unsigned short* __restrict__ Bm,
                                                   float* __restrict__ out) {
  const int be = blockIdx.x & 7;   // fixed e-panel per XCD (L2 locality for Wf)
  const int bm = blockIdx.x >> 3;
  const int tid = threadIdx.x;
  const int w = tid >> 6, l = tid & 63;
  const int l16 = l & 15, lg = l >> 4;
  const int wm = w >> 1, wn = w & 1;

  __shared__ __align__(16) unsigned short As[128][72];
  __shared__ __align__(16) unsigned short Bs[128][72];

  f32x4 acc[4][4] = {};
  const int m0 = bm * 128, e0 = be * 128;
  const int srow = tid >> 3, sc8 = (tid & 7) * 8;
  const unsigned short* Ab = A + (size_t)(m0 + srow) * E_ + sc8;
  const unsigned short* Bb = Bm + (size_t)(e0 + srow) * E_ + sc8;

  uint4v ar[4], br[4];
#pragma unroll
  for (int i = 0; i < 4; ++i) {
    ar[i] = *(const uint4v*)(Ab + (size_t)i * 32 * E_);
    br[i] = *(const uint4v*)(Bb + (size_t)i * 32 * E_);
  }

  for (int kk = 0; kk < 16; ++kk) {
    __syncthreads();  // prev-tile reads done (and prefetch drained)
#pragma unroll
    for (int i = 0; i < 4; ++i) {
      *(ushort8*)&As[i * 32 + srow][sc8] = __builtin_bit_cast(ushort8, ar[i]);
      *(ushort8*)&Bs[i * 32 + srow][sc8] = __builtin_bit_cast(ushort8, br[i]);
    }
    __syncthreads();  // tile ready
    if (kk < 15) {    // issue next-tile loads; overlap with MFMAs below
#pragma unroll
      for (int i = 0; i < 4; ++i) {
        ar[i] = *(const uint4v*)(Ab + (size_t)i * 32 * E_ + (kk + 1) * 64);
        br[i] = *(const uint4v*)(Bb + (size_t)i * 32 * E_ + (kk + 1) * 64);
      }
    }
#pragma unroll
    for (int kc = 0; kc < 2; ++kc) {
      ushort8 a[4], bf[4];
#pragma unroll
      for (int i = 0; i < 4; ++i)
        a[i] = *(const ushort8*)&As[wm * 64 + i * 16 + l16][kc * 32 + lg * 8];
#pragma unroll
      for (int j = 0; j < 4; ++j)
        bf[j] = *(const ushort8*)&Bs[wn * 64 + j * 16 + l16][kc * 32 + lg * 8];
#pragma unroll
      for (int i = 0; i < 4; ++i)
#pragma unroll
        for (int j = 0; j < 4; ++j) acc[i][j] = mfma16(a[i], bf[j], acc[i][j]);
    }
  }

#pragma unroll
  for (int i = 0; i < 4; ++i)
#pragma unroll
    for (int j = 0; j < 4; ++j)
#pragma unroll
      for (int r = 0; r < 4; ++r)
        out[(size_t)(m0 + wm * 64 + i * 16 + lg * 4 + r) * E_ + e0 + wn * 64 + j * 16 + l16] =
            acc[i][j][r];
}

extern "C" void kernel_launch(void* const* d_in, const int* in_sizes, int n_in,
                              void* d_out, int out_size, void* d_ws, size_t ws_size,
                              hipStream_t stream) {
  const float* q = (const float*)d_in[0];
  const float* k = (const float*)d_in[1];
  const float* v = (const float*)d_in[2];
  const float* mask = (const float*)d_in[3];
  const float* Wq = (const float*)d_in[4];
  const float* Wk = (const float*)d_in[5];
  const float* Wv = (const float*)d_in[6];
  const float* Wf = (const float*)d_in[7];
  float* out = (float*)d_out;

  const size_t PH = (size_t)B_ * H_ * N_ * D_;
  unsigned short* Qh = (unsigned short*)d_ws;
  unsigned short* Kh = Qh + PH;
  unsigned short* Vt = Kh + PH;
  unsigned short* attn = Vt + PH;
  unsigned short* Wfb = attn + PH;

  wf_kernel<<<(E_ * E_) / (256 * 4), 256, 0, stream>>>(Wf, Wfb);
  proj_kernel<<<B_ * H_ * (N_ / 64), 256, 0, stream>>>(q, k, v, Wq, Wk, Wv, Qh, Kh, Vt);
  attn_kernel<<<B_ * H_ * (N_ / 128), 256, 0, stream>>>(Qh, Kh, Vt, mask, attn);
  gemm_kernel<<<(B_ * N_ / 128) * (E_ / 128), 256, 0, stream>>>(attn, Wfb, out);
}

// Round 6
// 153.474 us; speedup vs baseline: 1.5436x; 1.0311x over previous
//
#include <hip/hip_runtime.h>

#define B_ 16
#define N_ 768
#define E_ 1024
#define H_ 16
#define D_ 64

typedef __bf16 bf16x8 __attribute__((ext_vector_type(8)));
typedef float f32x4 __attribute__((ext_vector_type(4)));
typedef unsigned short ushort8 __attribute__((ext_vector_type(8)));
typedef unsigned short ushort4v __attribute__((ext_vector_type(4)));
typedef unsigned int uint2v __attribute__((ext_vector_type(2)));
typedef unsigned int uint4v __attribute__((ext_vector_type(4)));

__device__ __forceinline__ unsigned short f2bf(float x) {
  unsigned u = __builtin_bit_cast(unsigned, x);
  u += 0x7FFFu + ((u >> 16) & 1u);
  return (unsigned short)(u >> 16);
}

__device__ __forceinline__ unsigned cvtpk(float lo, float hi) {
  unsigned r;
  asm("v_cvt_pk_bf16_f32 %0, %1, %2" : "=v"(r) : "v"(lo), "v"(hi));
  return r;
}

__device__ __forceinline__ f32x4 mfma16(ushort8 a, ushort8 b, f32x4 c) {
  return __builtin_amdgcn_mfma_f32_16x16x32_bf16(
      __builtin_bit_cast(bf16x8, a), __builtin_bit_cast(bf16x8, b), c, 0, 0, 0);
}

// ---------------- per-head projections (MFMA), R1-verified, + Wf conversion ----------------
// Qh,Kh in (B,H,N,D) bf16; V written TRANSPOSED as Vt (B,H,D,N) bf16.
// Blocks 0..1023 additionally convert a 4KB chunk of Wf to bf16 (disjoint, no sync).
__global__ __launch_bounds__(256) void proj_kernel(
    const float* __restrict__ q, const float* __restrict__ k, const float* __restrict__ v,
    const float* __restrict__ Wq, const float* __restrict__ Wk, const float* __restrict__ Wv,
    const float* __restrict__ Wf, unsigned short* __restrict__ Qh,
    unsigned short* __restrict__ Kh, unsigned short* __restrict__ Vt,
    unsigned short* __restrict__ Wfb) {
  const int nt = blockIdx.x % 12;
  const int bh = blockIdx.x / 12;
  const int b = bh >> 4, h = bh & 15;
  const int tid = threadIdx.x;
  const int w = tid >> 6, l = tid & 63;
  const int l16 = l & 15, lg = l >> 4;

  if (blockIdx.x < 1024) {  // fused Wf -> bf16 (independent elementwise)
    size_t g = (size_t)blockIdx.x * 256 + tid;
    float4 xv = *(const float4*)&Wf[g * 4];
    ushort4v s;
    s[0] = f2bf(xv.x); s[1] = f2bf(xv.y); s[2] = f2bf(xv.z); s[3] = f2bf(xv.w);
    *(ushort4v*)&Wfb[g * 4] = s;
  }

  __shared__ __align__(16) unsigned short Xs[3][64][72];
  __shared__ __align__(16) unsigned short Ws[3][64][72];

  const float* xin[3] = {q, k, v};
  const float* win[3] = {Wq, Wk, Wv};

#pragma unroll
  for (int m = 0; m < 3; ++m) {
    const float* xp = xin[m];
#pragma unroll
    for (int i = 0; i < 4; ++i) {
      int flat = i * 256 + tid;
      int row = flat >> 4;
      int c4 = (flat & 15) * 4;
      float4 xv = *(const float4*)&xp[((size_t)(b * N_ + nt * 64 + row)) * E_ + h * 64 + c4];
      ushort4v s;
      s[0] = f2bf(xv.x); s[1] = f2bf(xv.y); s[2] = f2bf(xv.z); s[3] = f2bf(xv.w);
      *(ushort4v*)&Xs[m][row][c4] = s;
    }
    const float* wp = win[m] + (size_t)h * 4096;
#pragma unroll
    for (int i = 0; i < 4; ++i) {
      int flat = i * 256 + tid;
      int row = flat >> 4;
      int c4 = (flat & 15) * 4;
      float4 wv = *(const float4*)&wp[row * 64 + c4];
      ushort4v s;
      s[0] = f2bf(wv.x); s[1] = f2bf(wv.y); s[2] = f2bf(wv.z); s[3] = f2bf(wv.w);
      *(ushort4v*)&Ws[m][row][c4] = s;
    }
  }
  __syncthreads();

  f32x4 vacc[4];
#pragma unroll
  for (int m = 0; m < 3; ++m) {
    f32x4 acc[4] = {};
#pragma unroll
    for (int kc = 0; kc < 2; ++kc) {
      ushort8 a = *(const ushort8*)&Xs[m][w * 16 + l16][kc * 32 + lg * 8];
#pragma unroll
      for (int eg = 0; eg < 4; ++eg) {
        ushort8 bf = *(const ushort8*)&Ws[m][eg * 16 + l16][kc * 32 + lg * 8];
        acc[eg] = mfma16(a, bf, acc[eg]);
      }
    }
    if (m == 2) {
#pragma unroll
      for (int eg = 0; eg < 4; ++eg) vacc[eg] = acc[eg];
    } else {
      unsigned short* op = (m == 0) ? Qh : Kh;
#pragma unroll
      for (int eg = 0; eg < 4; ++eg)
#pragma unroll
        for (int r = 0; r < 4; ++r)
          op[((size_t)(b * H_ + h) * N_ + nt * 64 + w * 16 + lg * 4 + r) * 64 + eg * 16 + l16] =
              f2bf(acc[eg][r]);
    }
  }

  // transpose V tile through LDS (reuse Xs[0]): rows d, cols n-local
  __syncthreads();
#pragma unroll
  for (int eg = 0; eg < 4; ++eg) {
    uint2v pk;
    pk[0] = cvtpk(vacc[eg][0], vacc[eg][1]);
    pk[1] = cvtpk(vacc[eg][2], vacc[eg][3]);
    *(uint2v*)&Xs[0][eg * 16 + l16][w * 16 + lg * 4] = pk;
  }
  __syncthreads();
#pragma unroll
  for (int i = 0; i < 2; ++i) {
    int row = i * 32 + (tid >> 3), c8 = (tid & 7) * 8;
    *(ushort8*)&Vt[((size_t)bh * 64 + row) * N_ + nt * 64 + c8] =
        *(const ushort8*)&Xs[0][row][c8];
  }
}

// ---------------- flash attention per (b,h,qtile=128) — R1-verified verbatim ----------------
// Swapped QK^T (S^T via mfma(K,Q)); fixed-shift softmax (no online max);
// deferred denominator; P packed via cvt_pk -> b64 LDS writes.
__global__ __launch_bounds__(256, 4) void attn_kernel(
    const unsigned short* __restrict__ Qh, const unsigned short* __restrict__ Kh,
    const unsigned short* __restrict__ Vt, const float* __restrict__ mask,
    unsigned short* __restrict__ attnO) {
  const int bid = blockIdx.x;
  const int logical = (bid & 7) * 192 + (bid >> 3);  // XCD-chunked swizzle (1536%8==0)
  const int qt = logical % 6;
  const int bh = logical / 6;
  const int b = bh >> 4, h = bh & 15;
  const int tid = threadIdx.x;
  const int w = tid >> 6, l = tid & 63;
  const int l16 = l & 15, lg = l >> 4;

  __shared__ __align__(16) unsigned short Ks[64][72];
  __shared__ __align__(16) unsigned short Vs[64][72];
  __shared__ __align__(16) unsigned short Ps[4][32][72];
  __shared__ float badk[N_];

  const size_t baseK = (size_t)bh * N_ * 64;  // Kh (B,H,N,D)
  const size_t baseV = (size_t)bh * 64 * N_;  // Vt (B,H,D,N)
  const int qrow0 = qt * 128 + w * 32;

  for (int i = tid; i < N_; i += 256) badk[i] = (mask[h * N_ + i] < -1e30f) ? 1.f : 0.f;

  // Q fragments direct from global (read once, reused 12x)
  ushort8 bQ[2][2];
#pragma unroll
  for (int qs = 0; qs < 2; ++qs)
#pragma unroll
    for (int kc = 0; kc < 2; ++kc)
      bQ[qs][kc] = *(const ushort8*)&Qh[((size_t)bh * N_ + qrow0 + qs * 16 + l16) * 64 +
                                        kc * 32 + lg * 8];
  float bqf[2];
#pragma unroll
  for (int qs = 0; qs < 2; ++qs)
    bqf[qs] = (mask[h * N_ + qrow0 + qs * 16 + l16] < -1e30f) ? 1.f : 0.f;

  const int srow = tid >> 3;          // 0..31 (+32 for i=1)
  const int sc8 = (tid & 7) * 8;

  uint4v kreg[2], vreg[2];
#pragma unroll
  for (int i = 0; i < 2; ++i) {
    int row = i * 32 + srow;
    kreg[i] = *(const uint4v*)&Kh[baseK + (size_t)row * 64 + sc8];
    vreg[i] = *(const uint4v*)&Vt[baseV + (size_t)row * N_ + sc8];
  }
  __syncthreads();  // badk ready
#pragma unroll
  for (int i = 0; i < 2; ++i) {
    int row = i * 32 + srow;
    *(ushort8*)&Ks[row][sc8] = __builtin_bit_cast(ushort8, kreg[i]);
    *(ushort8*)&Vs[row][sc8] = __builtin_bit_cast(ushort8, vreg[i]);
  }
  __syncthreads();

  f32x4 oacc[2][4] = {};
  float l_part[2] = {0.f, 0.f};

  for (int kt = 0; kt < 12; ++kt) {
    if (kt < 11) {  // T14: issue next-tile loads early, write after barrier
#pragma unroll
      for (int i = 0; i < 2; ++i) {
        int row = i * 32 + srow;
        kreg[i] = *(const uint4v*)&Kh[baseK + (size_t)((kt + 1) * 64 + row) * 64 + sc8];
        vreg[i] = *(const uint4v*)&Vt[baseV + (size_t)row * N_ + (kt + 1) * 64 + sc8];
      }
    }

    // S^T tile-by-16 + softmax + pack (keeps register pressure low)
#pragma unroll
    for (int cg = 0; cg < 4; ++cg) {
      f32x4 st[2] = {};
#pragma unroll
      for (int kc = 0; kc < 2; ++kc) {
        ushort8 aK = *(const ushort8*)&Ks[cg * 16 + l16][kc * 32 + lg * 8];
        st[0] = mfma16(aK, bQ[0][kc], st[0]);
        st[1] = mfma16(aK, bQ[1][kc], st[1]);
      }
      f32x4 bk4 = *(const f32x4*)&badk[kt * 64 + cg * 16 + lg * 4];
#pragma unroll
      for (int qs = 0; qs < 2; ++qs) {
        float p[4];
#pragma unroll
        for (int r = 0; r < 4; ++r) {
          float t = st[qs][r] * 0.03125f;      // 1/sqrt(E)
          t = (bk4[r] > 0.f) ? -1e16f : t;     // masked k -> exp = 0
          t = (bqf[qs] > 0.f) ? 0.f : t;       // bad q row -> uniform
          p[r] = __expf(t);
          l_part[qs] += p[r];
        }
        uint2v pk;
        pk[0] = cvtpk(p[0], p[1]);
        pk[1] = cvtpk(p[2], p[3]);
        *(uint2v*)&Ps[w][qs * 16 + l16][cg * 16 + lg * 4] = pk;
      }
    }

    // O += P V
#pragma unroll
    for (int kc = 0; kc < 2; ++kc) {
      ushort8 ap[2];
#pragma unroll
      for (int qs = 0; qs < 2; ++qs)
        ap[qs] = *(const ushort8*)&Ps[w][qs * 16 + l16][kc * 32 + lg * 8];
#pragma unroll
      for (int dg = 0; dg < 4; ++dg) {
        ushort8 bv = *(const ushort8*)&Vs[dg * 16 + l16][kc * 32 + lg * 8];
        oacc[0][dg] = mfma16(ap[0], bv, oacc[0][dg]);
        oacc[1][dg] = mfma16(ap[1], bv, oacc[1][dg]);
      }
    }

    __syncthreads();
    if (kt < 11) {
#pragma unroll
      for (int i = 0; i < 2; ++i) {
        int row = i * 32 + srow;
        *(ushort8*)&Ks[row][sc8] = __builtin_bit_cast(ushort8, kreg[i]);
        *(ushort8*)&Vs[row][sc8] = __builtin_bit_cast(ushort8, vreg[i]);
      }
    }
    __syncthreads();
  }

  // epilogue: denominator reduce + write
#pragma unroll
  for (int qs = 0; qs < 2; ++qs) {
    float s = l_part[qs];
    s += __shfl_xor(s, 16);
    s += __shfl_xor(s, 32);
#pragma unroll
    for (int r = 0; r < 4; ++r) {
      float dnm = __shfl(s, lg * 4 + r);
      float inv = 1.f / dnm;
      int qg = qrow0 + qs * 16 + lg * 4 + r;
      size_t orow = ((size_t)b * N_ + qg) * E_ + h * 64;
#pragma unroll
      for (int dg = 0; dg < 4; ++dg)
        attnO[orow + dg * 16 + l16] = f2bf(oacc[qs][dg][r] * inv);
    }
  }
}

// ---------------- final GEMM: out = attn @ Wf^T — R2-verified T14 version ----------------
__global__ __launch_bounds__(256) void gemm_kernel(const unsigned short* __restrict__ A,
                                                   const unsigned short* __restrict__ Bm,
                                                   float* __restrict__ out) {
  const int be = blockIdx.x & 7;   // Wf panel per XCD (L2 locality)
  const int bm = blockIdx.x >> 3;
  const int tid = threadIdx.x;
  const int w = tid >> 6, l = tid & 63;
  const int l16 = l & 15, lg = l >> 4;
  const int wm = w >> 1, wn = w & 1;

  __shared__ __align__(16) unsigned short As[128][72];
  __shared__ __align__(16) unsigned short Bs[128][72];

  f32x4 acc[4][4] = {};
  const int m0 = bm * 128, e0 = be * 128;
  const int srow = tid >> 3, sc8 = (tid & 7) * 8;
  const unsigned short* Ab = A + (size_t)(m0 + srow) * E_ + sc8;
  const unsigned short* Bb = Bm + (size_t)(e0 + srow) * E_ + sc8;

  uint4v ar[4], br[4];
#pragma unroll
  for (int i = 0; i < 4; ++i) {
    ar[i] = *(const uint4v*)(Ab + (size_t)i * 32 * E_);
    br[i] = *(const uint4v*)(Bb + (size_t)i * 32 * E_);
  }

  for (int kk = 0; kk < 16; ++kk) {
    __syncthreads();  // prev-tile reads done
#pragma unroll
    for (int i = 0; i < 4; ++i) {
      *(ushort8*)&As[i * 32 + srow][sc8] = __builtin_bit_cast(ushort8, ar[i]);
      *(ushort8*)&Bs[i * 32 + srow][sc8] = __builtin_bit_cast(ushort8, br[i]);
    }
    __syncthreads();  // tile ready
    if (kk < 15) {    // issue next-tile loads; overlap with MFMAs below
#pragma unroll
      for (int i = 0; i < 4; ++i) {
        ar[i] = *(const uint4v*)(Ab + (size_t)i * 32 * E_ + (kk + 1) * 64);
        br[i] = *(const uint4v*)(Bb + (size_t)i * 32 * E_ + (kk + 1) * 64);
      }
    }
#pragma unroll
    for (int kc = 0; kc < 2; ++kc) {
      ushort8 a[4], bf[4];
#pragma unroll
      for (int i = 0; i < 4; ++i)
        a[i] = *(const ushort8*)&As[wm * 64 + i * 16 + l16][kc * 32 + lg * 8];
#pragma unroll
      for (int j = 0; j < 4; ++j)
        bf[j] = *(const ushort8*)&Bs[wn * 64 + j * 16 + l16][kc * 32 + lg * 8];
#pragma unroll
      for (int i = 0; i < 4; ++i)
#pragma unroll
        for (int j = 0; j < 4; ++j) acc[i][j] = mfma16(a[i], bf[j], acc[i][j]);
    }
  }

#pragma unroll
  for (int i = 0; i < 4; ++i)
#pragma unroll
    for (int j = 0; j < 4; ++j)
#pragma unroll
      for (int r = 0; r < 4; ++r)
        out[(size_t)(m0 + wm * 64 + i * 16 + lg * 4 + r) * E_ + e0 + wn * 64 + j * 16 + l16] =
            acc[i][j][r];
}

extern "C" void kernel_launch(void* const* d_in, const int* in_sizes, int n_in,
                              void* d_out, int out_size, void* d_ws, size_t ws_size,
                              hipStream_t stream) {
  const float* q = (const float*)d_in[0];
  const float* k = (const float*)d_in[1];
  const float* v = (const float*)d_in[2];
  const float* mask = (const float*)d_in[3];
  const float* Wq = (const float*)d_in[4];
  const float* Wk = (const float*)d_in[5];
  const float* Wv = (const float*)d_in[6];
  const float* Wf = (const float*)d_in[7];
  float* out = (float*)d_out;

  const size_t PH = (size_t)B_ * H_ * N_ * D_;
  unsigned short* Qh = (unsigned short*)d_ws;
  unsigned short* Kh = Qh + PH;
  unsigned short* Vt = Kh + PH;
  unsigned short* attn = Vt + PH;
  unsigned short* Wfb = attn + PH;

  proj_kernel<<<B_ * H_ * (N_ / 64), 256, 0, stream>>>(q, k, v, Wq, Wk, Wv, Wf, Qh, Kh, Vt,
                                                       Wfb);
  attn_kernel<<<B_ * H_ * (N_ / 128), 256, 0, stream>>>(Qh, Kh, Vt, mask, attn);
  gemm_kernel<<<(B_ * N_ / 128) * (E_ / 128), 256, 0, stream>>>(attn, Wfb, out);
}